// Round 15
// baseline (771.398 us; speedup 1.0000x reference)
//
#include <hip/hip_runtime.h>

#define N_NODES 100000
#define N_EDGES 1600000
#define DF 128
#define NL 3
#define NG 128
#define NC 2
#define BN_EPS 1e-5f
#define GEMM_BLOCKS ((N_NODES + 127) / 128)   // 782
#define GE_SLICES 16

// ---- bucket sort params ----
#define NBKT 98                               // dst >> 10  -> 0..97
#define NBIN_BLOCKS 512
#define EDGES_PER_BLOCK (N_EDGES / NBIN_BLOCKS)  // 3125

typedef unsigned int u32;
typedef unsigned short u16;
typedef unsigned long long u64;

using bf16x8 = __attribute__((ext_vector_type(8))) short;
using f32x4  = __attribute__((ext_vector_type(4))) float;

__device__ __forceinline__ u16 f2bf(float f) {
    u32 u = __float_as_uint(f);
    u32 r = (u + 0x7FFFu + ((u >> 16) & 1u)) >> 16;
    return (u16)r;
}
__device__ __forceinline__ float bflo(u32 v) { return __uint_as_float(v << 16); }
__device__ __forceinline__ float bfhi(u32 v) { return __uint_as_float(v & 0xFFFF0000u); }

// ---------------- fp32 x -> row-major bf16 mirror ----------------
__global__ __launch_bounds__(256) void cvt_x_kernel(const float* __restrict__ x,
                                                    u16* __restrict__ xb) {
    size_t i4 = (size_t)blockIdx.x * 256 + threadIdx.x;   // one float4 / thread
    float4 v = ((const float4*)x)[i4];
    u32 lo = (u32)f2bf(v.x) | ((u32)f2bf(v.y) << 16);
    u32 hi = (u32)f2bf(v.z) | ((u32)f2bf(v.w) << 16);
    ((uint2*)xb)[i4] = make_uint2(lo, hi);
}

// ---------------- CSR build via 2-level bucket sort ----------------
__global__ __launch_bounds__(256) void bin_count_kernel(const int* __restrict__ dst,
                                                        int* __restrict__ blkhist) {
    __shared__ int hist[NBKT];
    int t = threadIdx.x, b = blockIdx.x;
    for (int i = t; i < NBKT; i += 256) hist[i] = 0;
    __syncthreads();
    int base = b * EDGES_PER_BLOCK;
    for (int i = t; i < EDGES_PER_BLOCK; i += 256)
        atomicAdd(&hist[dst[base + i] >> 10], 1);
    __syncthreads();
    for (int i = t; i < NBKT; i += 256) blkhist[i * NBIN_BLOCKS + b] = hist[i];
}

__global__ __launch_bounds__(512) void binscanA_kernel(int* __restrict__ blkhist,
                                                       int* __restrict__ bkt_total) {
    __shared__ int buf[NBIN_BLOCKS];
    int bucket = blockIdx.x, t = threadIdx.x;
    int v = blkhist[bucket * NBIN_BLOCKS + t];
    buf[t] = v;
    __syncthreads();
    for (int off = 1; off < NBIN_BLOCKS; off <<= 1) {
        int tv = (t >= off) ? buf[t - off] : 0;
        __syncthreads();
        buf[t] += tv;
        __syncthreads();
    }
    blkhist[bucket * NBIN_BLOCKS + t] = buf[t] - v;   // exclusive within bucket
    if (t == NBIN_BLOCKS - 1) bkt_total[bucket] = buf[t];
}

__global__ __launch_bounds__(128) void binscanB_kernel(const int* __restrict__ bkt_total,
                                                       int* __restrict__ bktbase) {
    __shared__ int buf[128];
    int t = threadIdx.x;
    int v = (t < NBKT) ? bkt_total[t] : 0;
    buf[t] = v;
    __syncthreads();
    for (int off = 1; off < 128; off <<= 1) {
        int tv = (t >= off) ? buf[t - off] : 0;
        __syncthreads();
        buf[t] += tv;
        __syncthreads();
    }
    if (t < NBKT) bktbase[t] = buf[t] - v;
    if (t == NBKT - 1) bktbase[NBKT] = buf[t];
}

__global__ __launch_bounds__(256) void bin_scatter_kernel(const int* __restrict__ src,
                                                          const int* __restrict__ dst,
                                                          const int* __restrict__ blkhist,
                                                          const int* __restrict__ bktbase,
                                                          u64* __restrict__ pairs) {
    __shared__ int lofs[NBKT];
    int t = threadIdx.x, b = blockIdx.x;
    for (int i = t; i < NBKT; i += 256)
        lofs[i] = bktbase[i] + blkhist[i * NBIN_BLOCKS + b];
    __syncthreads();
    int base = b * EDGES_PER_BLOCK;
    for (int i = t; i < EDGES_PER_BLOCK; i += 256) {
        int d = dst[base + i];
        int s = src[base + i];
        int p = atomicAdd(&lofs[d >> 10], 1);
        pairs[p] = ((u64)(u32)d << 32) | (u32)s;
    }
}

// ---------------- per-bucket CSR finalize: offsets + adj in ONE kernel ----------------
__global__ __launch_bounds__(1024) void csr_build_kernel(const u64* __restrict__ pairs,
                                                         const int* __restrict__ bktbase,
                                                         int* __restrict__ offsets,
                                                         int* __restrict__ adj) {
    __shared__ int cnt[1024];
    __shared__ int buf[1024];
    int b = blockIdx.x, t = threadIdx.x;
    int nbase = b << 10;
    int pb = bktbase[b], pe = bktbase[b + 1];
    cnt[t] = 0;
    __syncthreads();
    for (int i = pb + t; i < pe; i += 1024)
        atomicAdd(&cnt[(int)(pairs[i] >> 32) - nbase], 1);
    __syncthreads();
    int v = cnt[t];
    buf[t] = v;
    __syncthreads();
    for (int off = 1; off < 1024; off <<= 1) {
        int tv = (t >= off) ? buf[t - off] : 0;
        __syncthreads();
        buf[t] += tv;
        __syncthreads();
    }
    int excl = buf[t] - v;
    int node = nbase + t;
    if (node < N_NODES) offsets[node] = pb + excl;
    if (b == NBKT - 1 && t == 0) offsets[N_NODES] = N_EDGES;
    cnt[t] = excl;          // reuse as cursor
    __syncthreads();
    for (int i = pb + t; i < pe; i += 1024) {
        u64 pr = pairs[i];
        int d = (int)(pr >> 32);
        int pos = atomicAdd(&cnt[d - nbase], 1);
        adj[pb + pos] = (int)(pr & 0xFFFFFFFFu);
    }
}

// ---------------- aggregation: one wave per node, 8-deep gather pipeline ----------------
__global__ __launch_bounds__(256) void agg_kernel(const u32* __restrict__ X,
                                                  const int* __restrict__ offsets,
                                                  const int* __restrict__ adj,
                                                  u32* __restrict__ out) {
    int node = blockIdx.x * 4 + (threadIdx.x >> 6);
    int l = threadIdx.x & 63;                    // lane handles 2 features (u32)
    const u32* Xl = X + l;
    u32 v = Xl[(size_t)node << 6];
    float s0 = bflo(v), s1 = bfhi(v);
    float t0 = 0.f, t1 = 0.f;
    int k = offsets[node], e = offsets[node + 1];
    for (; k + 8 <= e; k += 8) {
        int a[8];
#pragma unroll
        for (int i = 0; i < 8; i++) a[i] = adj[k + i];
        u32 u[8];
#pragma unroll
        for (int i = 0; i < 8; i++) u[i] = Xl[(size_t)a[i] << 6];
#pragma unroll
        for (int i = 0; i < 8; i += 2) {
            s0 += bflo(u[i]);     s1 += bfhi(u[i]);
            t0 += bflo(u[i + 1]); t1 += bfhi(u[i + 1]);
        }
    }
    if (k + 4 <= e) {
        int a0 = adj[k + 0], a1 = adj[k + 1], a2 = adj[k + 2], a3 = adj[k + 3];
        u32 u0 = Xl[(size_t)a0 << 6];
        u32 u1 = Xl[(size_t)a1 << 6];
        u32 u2 = Xl[(size_t)a2 << 6];
        u32 u3 = Xl[(size_t)a3 << 6];
        s0 += bflo(u0); s1 += bfhi(u0);
        t0 += bflo(u1); t1 += bfhi(u1);
        s0 += bflo(u2); s1 += bfhi(u2);
        t0 += bflo(u3); t1 += bfhi(u3);
        k += 4;
    }
    for (; k < e; k++) {
        u32 u = Xl[(size_t)adj[k] << 6];
        s0 += bflo(u); s1 += bfhi(u);
    }
    out[((size_t)node << 6) + l] = (u32)f2bf(s0 + t0) | ((u32)f2bf(s1 + t1) << 16);
}

// ---------------- bf16 MFMA GEMM: out[N x 128] = A[N x 128] @ W^T + bias ----------------
// Wt: bf16 transposed [col][k] in swizzled LDS. A fragments loaded DIRECTLY from global.
// bf16 output path stages the 128x128 tile in LDS (swizzled) and stores coalesced uint4
// -- the direct fragment-layout store was 64x 2B scattered stores/thread (epilogue-bound).
// Column stats written as per-block partials (coalesced, no atomics).
template <int OUT_BF16>
__global__ __launch_bounds__(256) void gemm_mfma_kernel(const u16* __restrict__ A,
                                                        const u16* __restrict__ Wt,
                                                        const float* __restrict__ bias,
                                                        void* __restrict__ outp,
                                                        float* __restrict__ psumB,
                                                        float* __restrict__ psqB, int nrows) {
    __shared__ __align__(16) u16 sW[16384];  // W staging, then bf16 output staging (32 KB)
    __shared__ float sred[1024];             // stats reduction buffer (4 KB)

    int tid = threadIdx.x;
    int rb = blockIdx.x * 128;

    // stage W (swizzled)
    {
        const uint4* g = (const uint4*)Wt;
#pragma unroll
        for (int p = 0; p < 8; p++) {
            int q = p * 256 + tid;
            int r = q >> 4, seg = q & 15;
            uint4 v = g[q];
            *(uint4*)((char*)sW + r * 256 + ((seg * 16) ^ ((r & 7) << 4))) = v;
        }
    }

    int l = tid & 63, w = tid >> 6;
    int lr = l & 15, lg = l >> 4;

    // preload all A fragments (8 x dwordx4 in flight)
    bf16x8 afr[2][4];
#pragma unroll
    for (int t = 0; t < 2; t++) {
        int grow = rb + w * 32 + t * 16 + lr;
        bool ok = grow < nrows;
#pragma unroll
        for (int kc = 0; kc < 4; kc++) {
            bf16x8 z = {0, 0, 0, 0, 0, 0, 0, 0};
            if (ok) z = *(const bf16x8*)(A + (size_t)grow * 128 + kc * 32 + lg * 8);
            afr[t][kc] = z;
        }
    }
    __syncthreads();

    f32x4 acc[2][8];
#pragma unroll
    for (int t = 0; t < 2; t++)
#pragma unroll
        for (int c = 0; c < 8; c++) acc[t][c] = (f32x4){0.f, 0.f, 0.f, 0.f};

#pragma unroll
    for (int kc = 0; kc < 4; kc++) {
        int kb2 = (kc * 32 + lg * 8) * 2;   // byte offset along k
        bf16x8 b[8];
#pragma unroll
        for (int c = 0; c < 8; c++) {
            int col = c * 16 + lr;
            b[c] = *(const bf16x8*)((const char*)sW + col * 256 + (kb2 ^ ((col & 7) << 4)));
        }
#pragma unroll
        for (int t = 0; t < 2; t++)
#pragma unroll
            for (int c = 0; c < 8; c++)
                acc[t][c] = __builtin_amdgcn_mfma_f32_16x16x32_bf16(afr[t][kc], b[c], acc[t][c], 0, 0, 0);
    }

    // epilogue: bias add, stats, store
    float bb[8];
#pragma unroll
    for (int c = 0; c < 8; c++) bb[c] = bias[c * 16 + lr];

    float sp[8], qp[8];
#pragma unroll
    for (int c = 0; c < 8; c++) { sp[c] = 0.f; qp[c] = 0.f; }

    if (OUT_BF16) {
        __syncthreads();   // sW (W staging) no longer read; reuse for output tile
#pragma unroll
        for (int t = 0; t < 2; t++) {
#pragma unroll
            for (int r = 0; r < 4; r++) {
                int row = w * 32 + t * 16 + lg * 4 + r;
                bool ok = (rb + row) < nrows;
#pragma unroll
                for (int c = 0; c < 8; c++) {
                    float v = acc[t][c][r] + bb[c];
                    int col = c * 16 + lr;
                    *(u16*)((char*)sW + ((row * 256 + col * 2) ^ ((row & 7) << 4))) = f2bf(v);
                    if (ok) { sp[c] += v; qp[c] += v * v; }
                }
            }
        }
        __syncthreads();
        // coalesced store: 8 x uint4 per thread (1KB/wave lines)
        u16* outB = (u16*)outp;
#pragma unroll
        for (int p = 0; p < 8; p++) {
            int q = p * 256 + tid;
            int row = q >> 4, seg = q & 15;
            int grow = rb + row;
            if (grow < nrows) {
                uint4 v = *(const uint4*)((char*)sW + ((row * 256 + seg * 16) ^ ((row & 7) << 4)));
                *(uint4*)(outB + (size_t)grow * 128 + seg * 8) = v;
            }
        }
    } else {
        float* outF = (float*)outp;
#pragma unroll
        for (int t = 0; t < 2; t++) {
#pragma unroll
            for (int r = 0; r < 4; r++) {
                int grow = rb + w * 32 + t * 16 + lg * 4 + r;
                bool ok = grow < nrows;
#pragma unroll
                for (int c = 0; c < 8; c++) {
                    float v = acc[t][c][r] + bb[c];
                    if (ok) {
                        outF[(size_t)grow * 128 + c * 16 + lr] = v;
                        sp[c] += v;
                        qp[c] += v * v;
                    }
                }
            }
        }
    }

#pragma unroll
    for (int c = 0; c < 8; c++) {
        sp[c] += __shfl_xor(sp[c], 16); sp[c] += __shfl_xor(sp[c], 32);
        qp[c] += __shfl_xor(qp[c], 16); qp[c] += __shfl_xor(qp[c], 32);
    }
    if (OUT_BF16) __syncthreads();   // ensure output-staging reads done before... (sred separate, but keep ordering cheap)
    if (lg == 0) {
#pragma unroll
        for (int c = 0; c < 8; c++) {
            sred[(((w * 8 + c) * 16) + lr) * 2 + 0] = sp[c];
            sred[(((w * 8 + c) * 16) + lr) * 2 + 1] = qp[c];
        }
    }
    __syncthreads();
    if (tid < 128) {
        int c = tid >> 4, r = tid & 15;
        float s = 0.f, q = 0.f;
#pragma unroll
        for (int ww = 0; ww < 4; ww++) {
            s += sred[(((ww * 8 + c) * 16) + r) * 2 + 0];
            q += sred[(((ww * 8 + c) * 16) + r) * 2 + 1];
        }
        psumB[blockIdx.x * 128 + tid] = s;
        psqB[blockIdx.x * 128 + tid] = q;
    }
}

// ---------------- stats reduce + fused BN2/outer-BN finalize ----------------
__global__ __launch_bounds__(256) void stats_reduce_fin2_kernel(const float* __restrict__ psumB,
                                                                const float* __restrict__ psqB,
                                                                const float* __restrict__ g,
                                                                const float* __restrict__ bt,
                                                                const float* __restrict__ og,
                                                                const float* __restrict__ ob,
                                                                float* __restrict__ scale,
                                                                float* __restrict__ shift) {
    int f = blockIdx.x;
    int t = threadIdx.x;
    float s = 0.f, q = 0.f;
    for (int b = t; b < GEMM_BLOCKS; b += 256) {
        s += psumB[b * 128 + f];
        q += psqB[b * 128 + f];
    }
#pragma unroll
    for (int off = 1; off < 64; off <<= 1) {
        s += __shfl_xor(s, off);
        q += __shfl_xor(q, off);
    }
    __shared__ float rs[4], rq[4];
    int w = t >> 6;
    if ((t & 63) == 0) { rs[w] = s; rq[w] = q; }
    __syncthreads();
    if (t == 0) {
        float S = rs[0] + rs[1] + rs[2] + rs[3];
        float Q = rq[0] + rq[1] + rq[2] + rq[3];
        float m = S / (float)N_NODES;
        float v = Q / (float)N_NODES - m * m;
        if (v < 0.f) v = 0.f;
        float r2 = rsqrtf(v + BN_EPS);
        float a = r2 * g[f];
        float vu = v * a * a;
        float r3 = rsqrtf(vu + BN_EPS);
        float sc = a * r3 * og[f];
        scale[f] = sc;
        shift[f] = ob[f] - m * sc;
    }
}

// ---------------- BN1 self-reducing finalize + W2 fold (128 blocks x 128 thr) ----------------
// Each block reduces the per-block partials itself (800KB, L2-resident, coalesced),
// computes sc1/sh1, then folds its output column j. Removes the stats_reduce<0> launch.
__global__ __launch_bounds__(128) void bnfold_kernel(const float* __restrict__ psumB,
                                                     const float* __restrict__ psqB,
                                                     const float* __restrict__ g,
                                                     const float* __restrict__ bt,
                                                     const float* __restrict__ W2,
                                                     const float* __restrict__ b2,
                                                     u16* __restrict__ W2ft,
                                                     float* __restrict__ b2f) {
    __shared__ float sc1[128], sh1[128];
    int k = threadIdx.x;
    int j = blockIdx.x;
    {
        float S = 0.f, Q = 0.f;
        for (int b = 0; b < GEMM_BLOCKS; b++) {
            S += psumB[b * 128 + k];
            Q += psqB[b * 128 + k];
        }
        float m = S / (float)N_NODES;
        float v = Q / (float)N_NODES - m * m;
        if (v < 0.f) v = 0.f;
        float r = rsqrtf(v + BN_EPS);
        float sc = r * g[k];
        sc1[k] = sc;
        sh1[k] = bt[k] - m * sc;
    }
    __syncthreads();
    float w = W2[k * 128 + j];
    W2ft[j * 128 + k] = f2bf(sc1[k] * w);
    float p = sh1[k] * w;
#pragma unroll
    for (int off = 1; off < 64; off <<= 1) p += __shfl_xor(p, off);
    __shared__ float r2[2];
    if ((k & 63) == 0) r2[k >> 6] = p;
    __syncthreads();
    if (k == 0) b2f[j] = b2[j] + r2[0] + r2[1];
}

// ---------------- weight prep: all layers at once ----------------
__global__ void w1_prep_kernel(const float* __restrict__ W, u16* __restrict__ Wt) {
    int q = blockIdx.x * 256 + threadIdx.x;   // 192 blocks x 256 = 3*16384
    int layer = q >> 14;
    int r = q & 16383;
    int j = r >> 7, k = r & 127;
    Wt[q] = f2bf(W[layer * 16384 + k * 128 + j]);
}

// ---------------- relu-affine, bf16 in -> bf16 out (layers 0..L-2) ----------------
__global__ __launch_bounds__(256) void relu_affine_bf16_kernel(const u16* __restrict__ Hb,
                                                               const float* __restrict__ scale,
                                                               const float* __restrict__ shift,
                                                               u16* __restrict__ xb) {
    size_t i4 = (size_t)blockIdx.x * 256 + threadIdx.x;   // 4 bf16 / thread
    int fb = ((int)(i4 & 31)) * 4;
    uint2 hv = ((const uint2*)Hb)[i4];
    float4 sc = *(const float4*)&scale[fb];
    float4 sh = *(const float4*)&shift[fb];
    float y0 = fmaxf(bflo(hv.x) * sc.x + sh.x, 0.f);
    float y1 = fmaxf(bfhi(hv.x) * sc.y + sh.y, 0.f);
    float y2 = fmaxf(bflo(hv.y) * sc.z + sh.z, 0.f);
    float y3 = fmaxf(bfhi(hv.y) * sc.w + sh.w, 0.f);
    u32 lo = (u32)f2bf(y0) | ((u32)f2bf(y1) << 16);
    u32 hi = (u32)f2bf(y2) | ((u32)f2bf(y3) << 16);
    ((uint2*)xb)[i4] = make_uint2(lo, hi);
}

// ---------------- relu-affine, final layer: fp32 in-place ----------------
__global__ __launch_bounds__(256) void relu_affine_final_kernel(float* __restrict__ H,
                                                                const float* __restrict__ scale,
                                                                const float* __restrict__ shift) {
    size_t i4 = (size_t)blockIdx.x * 256 + threadIdx.x;
    int fb = ((int)(i4 & 31)) * 4;
    float4 h = ((const float4*)H)[i4];
    float4 sc = *(const float4*)&scale[fb];
    float4 sh = *(const float4*)&shift[fb];
    float4 y;
    y.x = fmaxf(h.x * sc.x + sh.x, 0.f);
    y.y = fmaxf(h.y * sc.y + sh.y, 0.f);
    y.z = fmaxf(h.z * sc.z + sh.z, 0.f);
    y.w = fmaxf(h.w * sc.w + sh.w, 0.f);
    ((float4*)H)[i4] = y;
}

// ---------------- readout ----------------
__global__ __launch_bounds__(128) void graph_embed_part_kernel(const float* __restrict__ X,
                                                               const float* __restrict__ w,
                                                               const int* __restrict__ batch,
                                                               float* __restrict__ gpart) {
    int g = blockIdx.x;
    int sl = blockIdx.y;
    int f = threadIdx.x;
    int lo = 0, hi = N_NODES;
    while (lo < hi) { int mid = (lo + hi) >> 1; if (batch[mid] < g) lo = mid + 1; else hi = mid; }
    int s = lo;
    lo = 0; hi = N_NODES;
    while (lo < hi) { int mid = (lo + hi) >> 1; if (batch[mid] < g + 1) lo = mid + 1; else hi = mid; }
    int e = lo;
    int cnt = e - s;
    int per = (cnt + GE_SLICES - 1) / GE_SLICES;
    int rs = s + sl * per;
    int re = rs + per; if (re > e) re = e;
    float acc = 0.f;
    for (int r = rs; r < re; r++) acc += X[(size_t)r * DF + f] * w[r];
    gpart[((size_t)g * GE_SLICES + sl) * DF + f] = acc;
}

__global__ __launch_bounds__(128) void graph_embed_reduce_kernel(const float* __restrict__ gpart,
                                                                 float* __restrict__ ge) {
    int g = blockIdx.x, f = threadIdx.x;
    float a = 0.f;
#pragma unroll
    for (int s = 0; s < GE_SLICES; s++) a += gpart[((size_t)g * GE_SLICES + s) * DF + f];
    ge[g * DF + f] = a;
}

__global__ void final_fc_kernel(const float* __restrict__ ge, const float* __restrict__ fcW,
                                const float* __restrict__ fcb, float* __restrict__ out) {
    int idx = blockIdx.x * blockDim.x + threadIdx.x;  // G*C = 256
    if (idx < NG * NC) {
        int g = idx / NC, c = idx % NC;
        float acc = fcb[c];
        for (int d = 0; d < DF; d++) acc += ge[g * DF + d] * fcW[d * NC + c];
        out[idx] = acc;
    }
}

// ---------------- launcher ----------------
extern "C" void kernel_launch(void* const* d_in, const int* in_sizes, int n_in,
                              void* d_out, int out_size, void* d_ws, size_t ws_size,
                              hipStream_t stream) {
    const float* x    = (const float*)d_in[0];
    const int*   ei   = (const int*)d_in[1];
    const int*   src  = ei;
    const int*   dst  = ei + N_EDGES;
    const float* nw   = (const float*)d_in[2];
    const int*   batch= (const int*)d_in[3];
    const float* W1   = (const float*)d_in[4];
    const float* b1   = (const float*)d_in[5];
    const float* g1   = (const float*)d_in[6];
    const float* bt1  = (const float*)d_in[7];
    const float* W2   = (const float*)d_in[8];
    const float* b2   = (const float*)d_in[9];
    const float* g2   = (const float*)d_in[10];
    const float* bt2  = (const float*)d_in[11];
    const float* og   = (const float*)d_in[12];
    const float* ob   = (const float*)d_in[13];
    const float* fcW  = (const float*)d_in[14];
    const float* fcb  = (const float*)d_in[15];

    float* out_f    = (float*)d_out;
    float* node_out = out_f;                              // N*DF fp32
    float* ge       = out_f + (size_t)N_NODES * DF;       // G*DF
    float* cls      = ge + NG * DF;                       // G*C

    char* w = (char*)d_ws;
    auto alloc = [&](size_t bytes) { char* p = w; w += (bytes + 255) & ~(size_t)255; return p; };

    u16*   XB      = (u16*)alloc((size_t)N_NODES * DF * 2);     // row-major bf16 features
    u16*   AGG     = (u16*)alloc((size_t)N_NODES * DF * 2);     // bf16 agg output / bf16 h2
    u16*   H1      = (u16*)alloc((size_t)N_NODES * DF * 2);     // bf16 h1_raw
    int*   offsets = (int*)alloc((size_t)(N_NODES + 1) * 4);
    int*   adj     = (int*)alloc((size_t)N_EDGES * 4);
    float* psumB   = (float*)alloc((size_t)GEMM_BLOCKS * 128 * 4);
    float* psqB    = (float*)alloc((size_t)GEMM_BLOCKS * 128 * 4);
    u16*   W1t     = (u16*)alloc((size_t)NL * 16384 * 2);
    u16*   W2ft    = (u16*)alloc(16384 * 2);
    float* b2f     = (float*)alloc(128 * 4);
    float* scaleO  = (float*)alloc(128 * 4);
    float* shiftO  = (float*)alloc(128 * 4);
    float* gpart   = (float*)alloc((size_t)NG * GE_SLICES * DF * 4);
    int*   blkhist = (int*)alloc((size_t)NBKT * NBIN_BLOCKS * 4);
    int*   bkt_tot = (int*)alloc(NBKT * 4);
    int*   bktbase = (int*)alloc((NBKT + 1) * 4);

    // pairs buffer (12.8MB) aliases AGG (dead until first agg_kernel)
    u64* pairs = (u64*)AGG;

    // bf16 mirror of input x + weight transposes
    cvt_x_kernel<<<12500, 256, 0, stream>>>(x, XB);
    w1_prep_kernel<<<192, 256, 0, stream>>>(W1, W1t);

    // ---- CSR build: bucket sort + one-shot per-bucket offsets/adj ----
    bin_count_kernel<<<NBIN_BLOCKS, 256, 0, stream>>>(dst, blkhist);
    binscanA_kernel<<<NBKT, NBIN_BLOCKS, 0, stream>>>(blkhist, bkt_tot);
    binscanB_kernel<<<1, 128, 0, stream>>>(bkt_tot, bktbase);
    bin_scatter_kernel<<<NBIN_BLOCKS, 256, 0, stream>>>(src, dst, blkhist, bktbase, pairs);
    csr_build_kernel<<<NBKT, 1024, 0, stream>>>(pairs, bktbase, offsets, adj);

    for (int l = 0; l < NL; l++) {
        // agg = X + sum_{in-edges} X[src]
        agg_kernel<<<N_NODES / 4, 256, 0, stream>>>((const u32*)XB, offsets, adj, (u32*)AGG);
        // h1_raw = agg @ W1 + b1 (bf16 out, LDS-transposed store) + per-block BN1 stats
        gemm_mfma_kernel<1><<<GEMM_BLOCKS, 256, 0, stream>>>(AGG, W1t + (size_t)l * 16384,
                                                             b1 + l * DF, H1, psumB, psqB,
                                                             N_NODES);
        // BN1 self-reducing finalize fused into W2 fold
        bnfold_kernel<<<128, 128, 0, stream>>>(psumB, psqB, g1 + l * DF, bt1 + l * DF,
                                               W2 + (size_t)l * DF * DF, b2 + l * DF, W2ft, b2f);
        // h2_raw = h1_raw @ W2f + b2f (+ per-block stats); bf16 for l<2, fp32 for final
        if (l < NL - 1) {
            gemm_mfma_kernel<1><<<GEMM_BLOCKS, 256, 0, stream>>>(H1, W2ft, b2f, AGG,
                                                                 psumB, psqB, N_NODES);
        } else {
            gemm_mfma_kernel<0><<<GEMM_BLOCKS, 256, 0, stream>>>(H1, W2ft, b2f, node_out,
                                                                 psumB, psqB, N_NODES);
        }
        // fused stats reduce + BN2/outer-BN finalize
        stats_reduce_fin2_kernel<<<128, 256, 0, stream>>>(psumB, psqB, g2 + l * DF, bt2 + l * DF,
                                                          og + l * DF, ob + l * DF,
                                                          scaleO, shiftO);
        if (l < NL - 1) {
            relu_affine_bf16_kernel<<<12500, 256, 0, stream>>>(AGG, scaleO, shiftO, XB);
        } else {
            relu_affine_final_kernel<<<12500, 256, 0, stream>>>(node_out, scaleO, shiftO);
        }
    }

    graph_embed_part_kernel<<<dim3(NG, GE_SLICES), 128, 0, stream>>>(node_out, nw, batch, gpart);
    graph_embed_reduce_kernel<<<NG, 128, 0, stream>>>(gpart, ge);
    final_fc_kernel<<<1, 256, 0, stream>>>(ge, fcW, fcb, cls);
}

// Round 16
// 456.261 us; speedup vs baseline: 1.6907x; 1.6907x over previous
//
#include <hip/hip_runtime.h>

#define N_NODES 100000
#define N_EDGES 1600000
#define DF 128
#define NL 3
#define NG 128
#define NC 2
#define BN_EPS 1e-5f
#define GEMM_BLOCKS ((N_NODES + 127) / 128)   // 782
#define GE_SLICES 16

// ---- bucket sort params ----
#define NBKT 98                               // dst >> 10  -> 0..97
#define NBIN_BLOCKS 512
#define EDGES_PER_BLOCK (N_EDGES / NBIN_BLOCKS)  // 3125

typedef unsigned int u32;
typedef unsigned short u16;
typedef unsigned long long u64;

using bf16x8 = __attribute__((ext_vector_type(8))) short;
using f32x4  = __attribute__((ext_vector_type(4))) float;

__device__ __forceinline__ u16 f2bf(float f) {
    u32 u = __float_as_uint(f);
    u32 r = (u + 0x7FFFu + ((u >> 16) & 1u)) >> 16;
    return (u16)r;
}
__device__ __forceinline__ float bflo(u32 v) { return __uint_as_float(v << 16); }
__device__ __forceinline__ float bfhi(u32 v) { return __uint_as_float(v & 0xFFFF0000u); }

// ---------------- fp32 x -> row-major bf16 mirror ----------------
__global__ __launch_bounds__(256) void cvt_x_kernel(const float* __restrict__ x,
                                                    u16* __restrict__ xb) {
    size_t i4 = (size_t)blockIdx.x * 256 + threadIdx.x;   // one float4 / thread
    float4 v = ((const float4*)x)[i4];
    u32 lo = (u32)f2bf(v.x) | ((u32)f2bf(v.y) << 16);
    u32 hi = (u32)f2bf(v.z) | ((u32)f2bf(v.w) << 16);
    ((uint2*)xb)[i4] = make_uint2(lo, hi);
}

// ---------------- CSR build via 2-level bucket sort ----------------
__global__ __launch_bounds__(256) void bin_count_kernel(const int* __restrict__ dst,
                                                        int* __restrict__ blkhist) {
    __shared__ int hist[NBKT];
    int t = threadIdx.x, b = blockIdx.x;
    for (int i = t; i < NBKT; i += 256) hist[i] = 0;
    __syncthreads();
    int base = b * EDGES_PER_BLOCK;
    for (int i = t; i < EDGES_PER_BLOCK; i += 256)
        atomicAdd(&hist[dst[base + i] >> 10], 1);
    __syncthreads();
    for (int i = t; i < NBKT; i += 256) blkhist[i * NBIN_BLOCKS + b] = hist[i];
}

__global__ __launch_bounds__(512) void binscanA_kernel(int* __restrict__ blkhist,
                                                       int* __restrict__ bkt_total) {
    __shared__ int buf[NBIN_BLOCKS];
    int bucket = blockIdx.x, t = threadIdx.x;
    int v = blkhist[bucket * NBIN_BLOCKS + t];
    buf[t] = v;
    __syncthreads();
    for (int off = 1; off < NBIN_BLOCKS; off <<= 1) {
        int tv = (t >= off) ? buf[t - off] : 0;
        __syncthreads();
        buf[t] += tv;
        __syncthreads();
    }
    blkhist[bucket * NBIN_BLOCKS + t] = buf[t] - v;   // exclusive within bucket
    if (t == NBIN_BLOCKS - 1) bkt_total[bucket] = buf[t];
}

__global__ __launch_bounds__(128) void binscanB_kernel(const int* __restrict__ bkt_total,
                                                       int* __restrict__ bktbase) {
    __shared__ int buf[128];
    int t = threadIdx.x;
    int v = (t < NBKT) ? bkt_total[t] : 0;
    buf[t] = v;
    __syncthreads();
    for (int off = 1; off < 128; off <<= 1) {
        int tv = (t >= off) ? buf[t - off] : 0;
        __syncthreads();
        buf[t] += tv;
        __syncthreads();
    }
    if (t < NBKT) bktbase[t] = buf[t] - v;
    if (t == NBKT - 1) bktbase[NBKT] = buf[t];
}

__global__ __launch_bounds__(256) void bin_scatter_kernel(const int* __restrict__ src,
                                                          const int* __restrict__ dst,
                                                          const int* __restrict__ blkhist,
                                                          const int* __restrict__ bktbase,
                                                          u64* __restrict__ pairs) {
    __shared__ int lofs[NBKT];
    int t = threadIdx.x, b = blockIdx.x;
    for (int i = t; i < NBKT; i += 256)
        lofs[i] = bktbase[i] + blkhist[i * NBIN_BLOCKS + b];
    __syncthreads();
    int base = b * EDGES_PER_BLOCK;
    for (int i = t; i < EDGES_PER_BLOCK; i += 256) {
        int d = dst[base + i];
        int s = src[base + i];
        int p = atomicAdd(&lofs[d >> 10], 1);
        pairs[p] = ((u64)(u32)d << 32) | (u32)s;
    }
}

// ---------------- per-bucket CSR finalize: offsets + adj in ONE kernel ----------------
__global__ __launch_bounds__(1024) void csr_build_kernel(const u64* __restrict__ pairs,
                                                         const int* __restrict__ bktbase,
                                                         int* __restrict__ offsets,
                                                         int* __restrict__ adj) {
    __shared__ int cnt[1024];
    __shared__ int buf[1024];
    int b = blockIdx.x, t = threadIdx.x;
    int nbase = b << 10;
    int pb = bktbase[b], pe = bktbase[b + 1];
    cnt[t] = 0;
    __syncthreads();
    for (int i = pb + t; i < pe; i += 1024)
        atomicAdd(&cnt[(int)(pairs[i] >> 32) - nbase], 1);
    __syncthreads();
    int v = cnt[t];
    buf[t] = v;
    __syncthreads();
    for (int off = 1; off < 1024; off <<= 1) {
        int tv = (t >= off) ? buf[t - off] : 0;
        __syncthreads();
        buf[t] += tv;
        __syncthreads();
    }
    int excl = buf[t] - v;
    int node = nbase + t;
    if (node < N_NODES) offsets[node] = pb + excl;
    if (b == NBKT - 1 && t == 0) offsets[N_NODES] = N_EDGES;
    cnt[t] = excl;          // reuse as cursor
    __syncthreads();
    for (int i = pb + t; i < pe; i += 1024) {
        u64 pr = pairs[i];
        int d = (int)(pr >> 32);
        int pos = atomicAdd(&cnt[d - nbase], 1);
        adj[pb + pos] = (int)(pr & 0xFFFFFFFFu);
    }
}

// ---------------- aggregation: one wave per node, 8-deep gather pipeline ----------------
__global__ __launch_bounds__(256) void agg_kernel(const u32* __restrict__ X,
                                                  const int* __restrict__ offsets,
                                                  const int* __restrict__ adj,
                                                  u32* __restrict__ out) {
    int node = blockIdx.x * 4 + (threadIdx.x >> 6);
    int l = threadIdx.x & 63;                    // lane handles 2 features (u32)
    const u32* Xl = X + l;
    u32 v = Xl[(size_t)node << 6];
    float s0 = bflo(v), s1 = bfhi(v);
    float t0 = 0.f, t1 = 0.f;
    int k = offsets[node], e = offsets[node + 1];
    for (; k + 8 <= e; k += 8) {
        int a[8];
#pragma unroll
        for (int i = 0; i < 8; i++) a[i] = adj[k + i];
        u32 u[8];
#pragma unroll
        for (int i = 0; i < 8; i++) u[i] = Xl[(size_t)a[i] << 6];
#pragma unroll
        for (int i = 0; i < 8; i += 2) {
            s0 += bflo(u[i]);     s1 += bfhi(u[i]);
            t0 += bflo(u[i + 1]); t1 += bfhi(u[i + 1]);
        }
    }
    if (k + 4 <= e) {
        int a0 = adj[k + 0], a1 = adj[k + 1], a2 = adj[k + 2], a3 = adj[k + 3];
        u32 u0 = Xl[(size_t)a0 << 6];
        u32 u1 = Xl[(size_t)a1 << 6];
        u32 u2 = Xl[(size_t)a2 << 6];
        u32 u3 = Xl[(size_t)a3 << 6];
        s0 += bflo(u0); s1 += bfhi(u0);
        t0 += bflo(u1); t1 += bfhi(u1);
        s0 += bflo(u2); s1 += bfhi(u2);
        t0 += bflo(u3); t1 += bfhi(u3);
        k += 4;
    }
    for (; k < e; k++) {
        u32 u = Xl[(size_t)adj[k] << 6];
        s0 += bflo(u); s1 += bfhi(u);
    }
    out[((size_t)node << 6) + l] = (u32)f2bf(s0 + t0) | ((u32)f2bf(s1 + t1) << 16);
}

// ---------------- bf16 MFMA GEMM: out[N x 128] = A[N x 128] @ W^T + bias ----------------
// Wt: bf16 transposed [col][k] in swizzled LDS. A fragments loaded DIRECTLY from global.
// bf16 output path stages the 128x128 tile in LDS (swizzled) and stores coalesced uint4.
// Column stats written as per-block partials (coalesced, no atomics).
template <int OUT_BF16>
__global__ __launch_bounds__(256) void gemm_mfma_kernel(const u16* __restrict__ A,
                                                        const u16* __restrict__ Wt,
                                                        const float* __restrict__ bias,
                                                        void* __restrict__ outp,
                                                        float* __restrict__ psumB,
                                                        float* __restrict__ psqB, int nrows) {
    __shared__ __align__(16) u16 sW[16384];  // W staging, then bf16 output staging (32 KB)
    __shared__ float sred[1024];             // stats reduction buffer (4 KB)

    int tid = threadIdx.x;
    int rb = blockIdx.x * 128;

    // stage W (swizzled)
    {
        const uint4* g = (const uint4*)Wt;
#pragma unroll
        for (int p = 0; p < 8; p++) {
            int q = p * 256 + tid;
            int r = q >> 4, seg = q & 15;
            uint4 v = g[q];
            *(uint4*)((char*)sW + r * 256 + ((seg * 16) ^ ((r & 7) << 4))) = v;
        }
    }

    int l = tid & 63, w = tid >> 6;
    int lr = l & 15, lg = l >> 4;

    // preload all A fragments (8 x dwordx4 in flight)
    bf16x8 afr[2][4];
#pragma unroll
    for (int t = 0; t < 2; t++) {
        int grow = rb + w * 32 + t * 16 + lr;
        bool ok = grow < nrows;
#pragma unroll
        for (int kc = 0; kc < 4; kc++) {
            bf16x8 z = {0, 0, 0, 0, 0, 0, 0, 0};
            if (ok) z = *(const bf16x8*)(A + (size_t)grow * 128 + kc * 32 + lg * 8);
            afr[t][kc] = z;
        }
    }
    __syncthreads();

    f32x4 acc[2][8];
#pragma unroll
    for (int t = 0; t < 2; t++)
#pragma unroll
        for (int c = 0; c < 8; c++) acc[t][c] = (f32x4){0.f, 0.f, 0.f, 0.f};

#pragma unroll
    for (int kc = 0; kc < 4; kc++) {
        int kb2 = (kc * 32 + lg * 8) * 2;   // byte offset along k
        bf16x8 b[8];
#pragma unroll
        for (int c = 0; c < 8; c++) {
            int col = c * 16 + lr;
            b[c] = *(const bf16x8*)((const char*)sW + col * 256 + (kb2 ^ ((col & 7) << 4)));
        }
#pragma unroll
        for (int t = 0; t < 2; t++)
#pragma unroll
            for (int c = 0; c < 8; c++)
                acc[t][c] = __builtin_amdgcn_mfma_f32_16x16x32_bf16(afr[t][kc], b[c], acc[t][c], 0, 0, 0);
    }

    // epilogue: bias add, stats, store
    float bb[8];
#pragma unroll
    for (int c = 0; c < 8; c++) bb[c] = bias[c * 16 + lr];

    float sp[8], qp[8];
#pragma unroll
    for (int c = 0; c < 8; c++) { sp[c] = 0.f; qp[c] = 0.f; }

    if (OUT_BF16) {
        __syncthreads();   // sW (W staging) no longer read; reuse for output tile
#pragma unroll
        for (int t = 0; t < 2; t++) {
#pragma unroll
            for (int r = 0; r < 4; r++) {
                int row = w * 32 + t * 16 + lg * 4 + r;
                bool ok = (rb + row) < nrows;
#pragma unroll
                for (int c = 0; c < 8; c++) {
                    float v = acc[t][c][r] + bb[c];
                    int col = c * 16 + lr;
                    *(u16*)((char*)sW + ((row * 256 + col * 2) ^ ((row & 7) << 4))) = f2bf(v);
                    if (ok) { sp[c] += v; qp[c] += v * v; }
                }
            }
        }
        __syncthreads();
        // coalesced store: 8 x uint4 per thread (1KB/wave lines)
        u16* outB = (u16*)outp;
#pragma unroll
        for (int p = 0; p < 8; p++) {
            int q = p * 256 + tid;
            int row = q >> 4, seg = q & 15;
            int grow = rb + row;
            if (grow < nrows) {
                uint4 v = *(const uint4*)((char*)sW + ((row * 256 + seg * 16) ^ ((row & 7) << 4)));
                *(uint4*)(outB + (size_t)grow * 128 + seg * 8) = v;
            }
        }
    } else {
        float* outF = (float*)outp;
#pragma unroll
        for (int t = 0; t < 2; t++) {
#pragma unroll
            for (int r = 0; r < 4; r++) {
                int grow = rb + w * 32 + t * 16 + lg * 4 + r;
                bool ok = grow < nrows;
#pragma unroll
                for (int c = 0; c < 8; c++) {
                    float v = acc[t][c][r] + bb[c];
                    if (ok) {
                        outF[(size_t)grow * 128 + c * 16 + lr] = v;
                        sp[c] += v;
                        qp[c] += v * v;
                    }
                }
            }
        }
    }

#pragma unroll
    for (int c = 0; c < 8; c++) {
        sp[c] += __shfl_xor(sp[c], 16); sp[c] += __shfl_xor(sp[c], 32);
        qp[c] += __shfl_xor(qp[c], 16); qp[c] += __shfl_xor(qp[c], 32);
    }
    if (lg == 0) {
#pragma unroll
        for (int c = 0; c < 8; c++) {
            sred[(((w * 8 + c) * 16) + lr) * 2 + 0] = sp[c];
            sred[(((w * 8 + c) * 16) + lr) * 2 + 1] = qp[c];
        }
    }
    __syncthreads();
    if (tid < 128) {
        int c = tid >> 4, r = tid & 15;
        float s = 0.f, q = 0.f;
#pragma unroll
        for (int ww = 0; ww < 4; ww++) {
            s += sred[(((ww * 8 + c) * 16) + r) * 2 + 0];
            q += sred[(((ww * 8 + c) * 16) + r) * 2 + 1];
        }
        psumB[blockIdx.x * 128 + tid] = s;
        psqB[blockIdx.x * 128 + tid] = q;
    }
}

// ---------------- stats reduce: 128 blocks (one per feature) x 256 thr ----------------
// MODE 0: outS/outQ = raw S,Q (consumed by bnfold).
// MODE 1: fused BN2+outer-BN finalize -> outS=scale, outQ=shift.
template <int MODE>
__global__ __launch_bounds__(256) void stats_reduce_kernel(const float* __restrict__ psumB,
                                                           const float* __restrict__ psqB,
                                                           const float* __restrict__ g,
                                                           const float* __restrict__ bt,
                                                           const float* __restrict__ og,
                                                           const float* __restrict__ ob,
                                                           float* __restrict__ outS,
                                                           float* __restrict__ outQ) {
    int f = blockIdx.x;
    int t = threadIdx.x;
    float s = 0.f, q = 0.f;
    for (int b = t; b < GEMM_BLOCKS; b += 256) {
        s += psumB[b * 128 + f];
        q += psqB[b * 128 + f];
    }
#pragma unroll
    for (int off = 1; off < 64; off <<= 1) {
        s += __shfl_xor(s, off);
        q += __shfl_xor(q, off);
    }
    __shared__ float rs[4], rq[4];
    int w = t >> 6;
    if ((t & 63) == 0) { rs[w] = s; rq[w] = q; }
    __syncthreads();
    if (t == 0) {
        float S = rs[0] + rs[1] + rs[2] + rs[3];
        float Q = rq[0] + rq[1] + rq[2] + rq[3];
        if (MODE == 0) {
            outS[f] = S;
            outQ[f] = Q;
        } else {
            float m = S / (float)N_NODES;
            float v = Q / (float)N_NODES - m * m;
            if (v < 0.f) v = 0.f;
            float r2 = rsqrtf(v + BN_EPS);
            float a = r2 * g[f];
            float vu = v * a * a;
            float r3 = rsqrtf(vu + BN_EPS);
            float sc = a * r3 * og[f];
            outS[f] = sc;
            outQ[f] = ob[f] - m * sc;
        }
    }
}

// ---------------- BN1 finalize fused into W2 fold (128 blocks x 128 thr) ----------------
// Consumes the PRE-REDUCED sF/qF (256 floats) -- the r15 self-reducing variant serialized
// 782x2 loads per block at 2.8% occupancy and cost 113us/dispatch.
__global__ __launch_bounds__(128) void bnfold_kernel(const float* __restrict__ psum,
                                                     const float* __restrict__ psq,
                                                     const float* __restrict__ g,
                                                     const float* __restrict__ bt,
                                                     const float* __restrict__ W2,
                                                     const float* __restrict__ b2,
                                                     u16* __restrict__ W2ft,
                                                     float* __restrict__ b2f) {
    __shared__ float sc1[128], sh1[128];
    int k = threadIdx.x;
    int j = blockIdx.x;
    {
        float S = psum[k], Q = psq[k];
        float m = S / (float)N_NODES;
        float v = Q / (float)N_NODES - m * m;
        if (v < 0.f) v = 0.f;
        float r = rsqrtf(v + BN_EPS);
        float sc = r * g[k];
        sc1[k] = sc;
        sh1[k] = bt[k] - m * sc;
    }
    __syncthreads();
    float w = W2[k * 128 + j];
    W2ft[j * 128 + k] = f2bf(sc1[k] * w);
    float p = sh1[k] * w;
#pragma unroll
    for (int off = 1; off < 64; off <<= 1) p += __shfl_xor(p, off);
    __shared__ float r2[2];
    if ((k & 63) == 0) r2[k >> 6] = p;
    __syncthreads();
    if (k == 0) b2f[j] = b2[j] + r2[0] + r2[1];
}

// ---------------- weight prep: all layers at once ----------------
__global__ void w1_prep_kernel(const float* __restrict__ W, u16* __restrict__ Wt) {
    int q = blockIdx.x * 256 + threadIdx.x;   // 192 blocks x 256 = 3*16384
    int layer = q >> 14;
    int r = q & 16383;
    int j = r >> 7, k = r & 127;
    Wt[q] = f2bf(W[layer * 16384 + k * 128 + j]);
}

// ---------------- relu-affine, bf16 in -> bf16 out (layers 0..L-2) ----------------
__global__ __launch_bounds__(256) void relu_affine_bf16_kernel(const u16* __restrict__ Hb,
                                                               const float* __restrict__ scale,
                                                               const float* __restrict__ shift,
                                                               u16* __restrict__ xb) {
    size_t i4 = (size_t)blockIdx.x * 256 + threadIdx.x;   // 4 bf16 / thread
    int fb = ((int)(i4 & 31)) * 4;
    uint2 hv = ((const uint2*)Hb)[i4];
    float4 sc = *(const float4*)&scale[fb];
    float4 sh = *(const float4*)&shift[fb];
    float y0 = fmaxf(bflo(hv.x) * sc.x + sh.x, 0.f);
    float y1 = fmaxf(bfhi(hv.x) * sc.y + sh.y, 0.f);
    float y2 = fmaxf(bflo(hv.y) * sc.z + sh.z, 0.f);
    float y3 = fmaxf(bfhi(hv.y) * sc.w + sh.w, 0.f);
    u32 lo = (u32)f2bf(y0) | ((u32)f2bf(y1) << 16);
    u32 hi = (u32)f2bf(y2) | ((u32)f2bf(y3) << 16);
    ((uint2*)xb)[i4] = make_uint2(lo, hi);
}

// ---------------- relu-affine, final layer: fp32 in-place ----------------
__global__ __launch_bounds__(256) void relu_affine_final_kernel(float* __restrict__ H,
                                                                const float* __restrict__ scale,
                                                                const float* __restrict__ shift) {
    size_t i4 = (size_t)blockIdx.x * 256 + threadIdx.x;
    int fb = ((int)(i4 & 31)) * 4;
    float4 h = ((const float4*)H)[i4];
    float4 sc = *(const float4*)&scale[fb];
    float4 sh = *(const float4*)&shift[fb];
    float4 y;
    y.x = fmaxf(h.x * sc.x + sh.x, 0.f);
    y.y = fmaxf(h.y * sc.y + sh.y, 0.f);
    y.z = fmaxf(h.z * sc.z + sh.z, 0.f);
    y.w = fmaxf(h.w * sc.w + sh.w, 0.f);
    ((float4*)H)[i4] = y;
}

// ---------------- readout ----------------
__global__ __launch_bounds__(128) void graph_embed_part_kernel(const float* __restrict__ X,
                                                               const float* __restrict__ w,
                                                               const int* __restrict__ batch,
                                                               float* __restrict__ gpart) {
    int g = blockIdx.x;
    int sl = blockIdx.y;
    int f = threadIdx.x;
    int lo = 0, hi = N_NODES;
    while (lo < hi) { int mid = (lo + hi) >> 1; if (batch[mid] < g) lo = mid + 1; else hi = mid; }
    int s = lo;
    lo = 0; hi = N_NODES;
    while (lo < hi) { int mid = (lo + hi) >> 1; if (batch[mid] < g + 1) lo = mid + 1; else hi = mid; }
    int e = lo;
    int cnt = e - s;
    int per = (cnt + GE_SLICES - 1) / GE_SLICES;
    int rs = s + sl * per;
    int re = rs + per; if (re > e) re = e;
    float acc = 0.f;
    for (int r = rs; r < re; r++) acc += X[(size_t)r * DF + f] * w[r];
    gpart[((size_t)g * GE_SLICES + sl) * DF + f] = acc;
}

__global__ __launch_bounds__(128) void graph_embed_reduce_kernel(const float* __restrict__ gpart,
                                                                 float* __restrict__ ge) {
    int g = blockIdx.x, f = threadIdx.x;
    float a = 0.f;
#pragma unroll
    for (int s = 0; s < GE_SLICES; s++) a += gpart[((size_t)g * GE_SLICES + s) * DF + f];
    ge[g * DF + f] = a;
}

__global__ void final_fc_kernel(const float* __restrict__ ge, const float* __restrict__ fcW,
                                const float* __restrict__ fcb, float* __restrict__ out) {
    int idx = blockIdx.x * blockDim.x + threadIdx.x;  // G*C = 256
    if (idx < NG * NC) {
        int g = idx / NC, c = idx % NC;
        float acc = fcb[c];
        for (int d = 0; d < DF; d++) acc += ge[g * DF + d] * fcW[d * NC + c];
        out[idx] = acc;
    }
}

// ---------------- launcher ----------------
extern "C" void kernel_launch(void* const* d_in, const int* in_sizes, int n_in,
                              void* d_out, int out_size, void* d_ws, size_t ws_size,
                              hipStream_t stream) {
    const float* x    = (const float*)d_in[0];
    const int*   ei   = (const int*)d_in[1];
    const int*   src  = ei;
    const int*   dst  = ei + N_EDGES;
    const float* nw   = (const float*)d_in[2];
    const int*   batch= (const int*)d_in[3];
    const float* W1   = (const float*)d_in[4];
    const float* b1   = (const float*)d_in[5];
    const float* g1   = (const float*)d_in[6];
    const float* bt1  = (const float*)d_in[7];
    const float* W2   = (const float*)d_in[8];
    const float* b2   = (const float*)d_in[9];
    const float* g2   = (const float*)d_in[10];
    const float* bt2  = (const float*)d_in[11];
    const float* og   = (const float*)d_in[12];
    const float* ob   = (const float*)d_in[13];
    const float* fcW  = (const float*)d_in[14];
    const float* fcb  = (const float*)d_in[15];

    float* out_f    = (float*)d_out;
    float* node_out = out_f;                              // N*DF fp32
    float* ge       = out_f + (size_t)N_NODES * DF;       // G*DF
    float* cls      = ge + NG * DF;                       // G*C

    char* w = (char*)d_ws;
    auto alloc = [&](size_t bytes) { char* p = w; w += (bytes + 255) & ~(size_t)255; return p; };

    u16*   XB      = (u16*)alloc((size_t)N_NODES * DF * 2);     // row-major bf16 features
    u16*   AGG     = (u16*)alloc((size_t)N_NODES * DF * 2);     // bf16 agg output / bf16 h2
    u16*   H1      = (u16*)alloc((size_t)N_NODES * DF * 2);     // bf16 h1_raw
    int*   offsets = (int*)alloc((size_t)(N_NODES + 1) * 4);
    int*   adj     = (int*)alloc((size_t)N_EDGES * 4);
    float* psumB   = (float*)alloc((size_t)GEMM_BLOCKS * 128 * 4);
    float* psqB    = (float*)alloc((size_t)GEMM_BLOCKS * 128 * 4);
    float* sF      = (float*)alloc(128 * 4);
    float* qF      = (float*)alloc(128 * 4);
    u16*   W1t     = (u16*)alloc((size_t)NL * 16384 * 2);
    u16*   W2ft    = (u16*)alloc(16384 * 2);
    float* b2f     = (float*)alloc(128 * 4);
    float* scaleO  = (float*)alloc(128 * 4);
    float* shiftO  = (float*)alloc(128 * 4);
    float* gpart   = (float*)alloc((size_t)NG * GE_SLICES * DF * 4);
    int*   blkhist = (int*)alloc((size_t)NBKT * NBIN_BLOCKS * 4);
    int*   bkt_tot = (int*)alloc(NBKT * 4);
    int*   bktbase = (int*)alloc((NBKT + 1) * 4);

    // pairs buffer (12.8MB) aliases AGG (dead until first agg_kernel)
    u64* pairs = (u64*)AGG;

    // bf16 mirror of input x + weight transposes
    cvt_x_kernel<<<12500, 256, 0, stream>>>(x, XB);
    w1_prep_kernel<<<192, 256, 0, stream>>>(W1, W1t);

    // ---- CSR build: bucket sort + one-shot per-bucket offsets/adj ----
    bin_count_kernel<<<NBIN_BLOCKS, 256, 0, stream>>>(dst, blkhist);
    binscanA_kernel<<<NBKT, NBIN_BLOCKS, 0, stream>>>(blkhist, bkt_tot);
    binscanB_kernel<<<1, 128, 0, stream>>>(bkt_tot, bktbase);
    bin_scatter_kernel<<<NBIN_BLOCKS, 256, 0, stream>>>(src, dst, blkhist, bktbase, pairs);
    csr_build_kernel<<<NBKT, 1024, 0, stream>>>(pairs, bktbase, offsets, adj);

    for (int l = 0; l < NL; l++) {
        // agg = X + sum_{in-edges} X[src]
        agg_kernel<<<N_NODES / 4, 256, 0, stream>>>((const u32*)XB, offsets, adj, (u32*)AGG);
        // h1_raw = agg @ W1 + b1 (bf16 out, LDS-transposed store) + per-block BN1 stats
        gemm_mfma_kernel<1><<<GEMM_BLOCKS, 256, 0, stream>>>(AGG, W1t + (size_t)l * 16384,
                                                             b1 + l * DF, H1, psumB, psqB,
                                                             N_NODES);
        // parallel stats reduce, then BN1 finalize fused into W2 fold
        stats_reduce_kernel<0><<<128, 256, 0, stream>>>(psumB, psqB, nullptr, nullptr,
                                                        nullptr, nullptr, sF, qF);
        bnfold_kernel<<<128, 128, 0, stream>>>(sF, qF, g1 + l * DF, bt1 + l * DF,
                                               W2 + (size_t)l * DF * DF, b2 + l * DF, W2ft, b2f);
        // h2_raw = h1_raw @ W2f + b2f (+ per-block stats); bf16 for l<2, fp32 for final
        if (l < NL - 1) {
            gemm_mfma_kernel<1><<<GEMM_BLOCKS, 256, 0, stream>>>(H1, W2ft, b2f, AGG,
                                                                 psumB, psqB, N_NODES);
        } else {
            gemm_mfma_kernel<0><<<GEMM_BLOCKS, 256, 0, stream>>>(H1, W2ft, b2f, node_out,
                                                                 psumB, psqB, N_NODES);
        }
        // fused stats reduce + BN2/outer-BN finalize
        stats_reduce_kernel<1><<<128, 256, 0, stream>>>(psumB, psqB, g2 + l * DF, bt2 + l * DF,
                                                        og + l * DF, ob + l * DF, scaleO, shiftO);
        if (l < NL - 1) {
            relu_affine_bf16_kernel<<<12500, 256, 0, stream>>>(AGG, scaleO, shiftO, XB);
        } else {
            relu_affine_final_kernel<<<12500, 256, 0, stream>>>(node_out, scaleO, shiftO);
        }
    }

    graph_embed_part_kernel<<<dim3(NG, GE_SLICES), 128, 0, stream>>>(node_out, nw, batch, gpart);
    graph_embed_reduce_kernel<<<NG, 128, 0, stream>>>(gpart, ge);
    final_fc_kernel<<<1, 256, 0, stream>>>(ge, fcW, fcb, cls);
}

// Round 17
// 432.179 us; speedup vs baseline: 1.7849x; 1.0557x over previous
//
#include <hip/hip_runtime.h>

#define N_NODES 100000
#define N_EDGES 1600000
#define DF 128
#define NL 3
#define NG 128
#define NC 2
#define BN_EPS 1e-5f
#define GEMM_BLOCKS ((N_NODES + 127) / 128)   // 782
#define GE_SLICES 16

// ---- bucket sort params ----
#define NBKT 98                               // dst >> 10  -> 0..97
#define NBIN_BLOCKS 512
#define EDGES_PER_BLOCK (N_EDGES / NBIN_BLOCKS)  // 3125

typedef unsigned int u32;
typedef unsigned short u16;
typedef unsigned long long u64;

using bf16x8 = __attribute__((ext_vector_type(8))) short;
using f32x4  = __attribute__((ext_vector_type(4))) float;

__device__ __forceinline__ u16 f2bf(float f) {
    u32 u = __float_as_uint(f);
    u32 r = (u + 0x7FFFu + ((u >> 16) & 1u)) >> 16;
    return (u16)r;
}
__device__ __forceinline__ float bflo(u32 v) { return __uint_as_float(v << 16); }
__device__ __forceinline__ float bfhi(u32 v) { return __uint_as_float(v & 0xFFFF0000u); }

// ---------------- fp32 x -> row-major bf16 mirror ----------------
__global__ __launch_bounds__(256) void cvt_x_kernel(const float* __restrict__ x,
                                                    u16* __restrict__ xb) {
    size_t i4 = (size_t)blockIdx.x * 256 + threadIdx.x;   // one float4 / thread
    float4 v = ((const float4*)x)[i4];
    u32 lo = (u32)f2bf(v.x) | ((u32)f2bf(v.y) << 16);
    u32 hi = (u32)f2bf(v.z) | ((u32)f2bf(v.w) << 16);
    ((uint2*)xb)[i4] = make_uint2(lo, hi);
}

// ---------------- CSR build via 2-level bucket sort ----------------
__global__ __launch_bounds__(256) void bin_count_kernel(const int* __restrict__ dst,
                                                        int* __restrict__ blkhist) {
    __shared__ int hist[NBKT];
    int t = threadIdx.x, b = blockIdx.x;
    for (int i = t; i < NBKT; i += 256) hist[i] = 0;
    __syncthreads();
    int base = b * EDGES_PER_BLOCK;
    for (int i = t; i < EDGES_PER_BLOCK; i += 256)
        atomicAdd(&hist[dst[base + i] >> 10], 1);
    __syncthreads();
    for (int i = t; i < NBKT; i += 256) blkhist[i * NBIN_BLOCKS + b] = hist[i];
}

__global__ __launch_bounds__(512) void binscanA_kernel(int* __restrict__ blkhist,
                                                       int* __restrict__ bkt_total) {
    __shared__ int buf[NBIN_BLOCKS];
    int bucket = blockIdx.x, t = threadIdx.x;
    int v = blkhist[bucket * NBIN_BLOCKS + t];
    buf[t] = v;
    __syncthreads();
    for (int off = 1; off < NBIN_BLOCKS; off <<= 1) {
        int tv = (t >= off) ? buf[t - off] : 0;
        __syncthreads();
        buf[t] += tv;
        __syncthreads();
    }
    blkhist[bucket * NBIN_BLOCKS + t] = buf[t] - v;   // exclusive within bucket
    if (t == NBIN_BLOCKS - 1) bkt_total[bucket] = buf[t];
}

__global__ __launch_bounds__(128) void binscanB_kernel(const int* __restrict__ bkt_total,
                                                       int* __restrict__ bktbase) {
    __shared__ int buf[128];
    int t = threadIdx.x;
    int v = (t < NBKT) ? bkt_total[t] : 0;
    buf[t] = v;
    __syncthreads();
    for (int off = 1; off < 128; off <<= 1) {
        int tv = (t >= off) ? buf[t - off] : 0;
        __syncthreads();
        buf[t] += tv;
        __syncthreads();
    }
    if (t < NBKT) bktbase[t] = buf[t] - v;
    if (t == NBKT - 1) bktbase[NBKT] = buf[t];
}

__global__ __launch_bounds__(256) void bin_scatter_kernel(const int* __restrict__ src,
                                                          const int* __restrict__ dst,
                                                          const int* __restrict__ blkhist,
                                                          const int* __restrict__ bktbase,
                                                          u64* __restrict__ pairs) {
    __shared__ int lofs[NBKT];
    int t = threadIdx.x, b = blockIdx.x;
    for (int i = t; i < NBKT; i += 256)
        lofs[i] = bktbase[i] + blkhist[i * NBIN_BLOCKS + b];
    __syncthreads();
    int base = b * EDGES_PER_BLOCK;
    for (int i = t; i < EDGES_PER_BLOCK; i += 256) {
        int d = dst[base + i];
        int s = src[base + i];
        int p = atomicAdd(&lofs[d >> 10], 1);
        pairs[p] = ((u64)(u32)d << 32) | (u32)s;
    }
}

// ---------------- per-bucket CSR finalize: offsets + adj in ONE kernel ----------------
__global__ __launch_bounds__(1024) void csr_build_kernel(const u64* __restrict__ pairs,
                                                         const int* __restrict__ bktbase,
                                                         int* __restrict__ offsets,
                                                         int* __restrict__ adj) {
    __shared__ int cnt[1024];
    __shared__ int buf[1024];
    int b = blockIdx.x, t = threadIdx.x;
    int nbase = b << 10;
    int pb = bktbase[b], pe = bktbase[b + 1];
    cnt[t] = 0;
    __syncthreads();
    for (int i = pb + t; i < pe; i += 1024)
        atomicAdd(&cnt[(int)(pairs[i] >> 32) - nbase], 1);
    __syncthreads();
    int v = cnt[t];
    buf[t] = v;
    __syncthreads();
    for (int off = 1; off < 1024; off <<= 1) {
        int tv = (t >= off) ? buf[t - off] : 0;
        __syncthreads();
        buf[t] += tv;
        __syncthreads();
    }
    int excl = buf[t] - v;
    int node = nbase + t;
    if (node < N_NODES) offsets[node] = pb + excl;
    if (b == NBKT - 1 && t == 0) offsets[N_NODES] = N_EDGES;
    cnt[t] = excl;          // reuse as cursor
    __syncthreads();
    for (int i = pb + t; i < pe; i += 1024) {
        u64 pr = pairs[i];
        int d = (int)(pr >> 32);
        int pos = atomicAdd(&cnt[d - nbase], 1);
        adj[pb + pos] = (int)(pr & 0xFFFFFFFFu);
    }
}

// ---------------- aggregation: one wave per node, 8-deep gather pipeline ----------------
// FUSED=1: input H is raw bf16 h2; apply x = relu(h*scale+shift) per element on the fly
// (replaces the relu_affine_bf16 pass: saves 100MB traffic + 2 launches). Still mem-bound.
template <int FUSED>
__global__ __launch_bounds__(256) void agg_kernel(const u32* __restrict__ X,
                                                  const int* __restrict__ offsets,
                                                  const int* __restrict__ adj,
                                                  const float* __restrict__ scale,
                                                  const float* __restrict__ shift,
                                                  u32* __restrict__ out) {
    int node = blockIdx.x * 4 + (threadIdx.x >> 6);
    int l = threadIdx.x & 63;                    // lane handles 2 features (u32)
    float sc0 = 1.f, sc1 = 1.f, sh0 = 0.f, sh1 = 0.f;
    if (FUSED) {
        sc0 = scale[2 * l];     sc1 = scale[2 * l + 1];
        sh0 = shift[2 * l];     sh1 = shift[2 * l + 1];
    }
    const u32* Xl = X + l;
#define CVT0(u) (FUSED ? fmaxf(bflo(u) * sc0 + sh0, 0.f) : bflo(u))
#define CVT1(u) (FUSED ? fmaxf(bfhi(u) * sc1 + sh1, 0.f) : bfhi(u))
    u32 v = Xl[(size_t)node << 6];
    float s0 = CVT0(v), s1 = CVT1(v);
    float t0 = 0.f, t1 = 0.f;
    int k = offsets[node], e = offsets[node + 1];
    for (; k + 8 <= e; k += 8) {
        int a[8];
#pragma unroll
        for (int i = 0; i < 8; i++) a[i] = adj[k + i];
        u32 u[8];
#pragma unroll
        for (int i = 0; i < 8; i++) u[i] = Xl[(size_t)a[i] << 6];
#pragma unroll
        for (int i = 0; i < 8; i += 2) {
            s0 += CVT0(u[i]);     s1 += CVT1(u[i]);
            t0 += CVT0(u[i + 1]); t1 += CVT1(u[i + 1]);
        }
    }
    if (k + 4 <= e) {
        int a0 = adj[k + 0], a1 = adj[k + 1], a2 = adj[k + 2], a3 = adj[k + 3];
        u32 u0 = Xl[(size_t)a0 << 6];
        u32 u1 = Xl[(size_t)a1 << 6];
        u32 u2 = Xl[(size_t)a2 << 6];
        u32 u3 = Xl[(size_t)a3 << 6];
        s0 += CVT0(u0); s1 += CVT1(u0);
        t0 += CVT0(u1); t1 += CVT1(u1);
        s0 += CVT0(u2); s1 += CVT1(u2);
        t0 += CVT0(u3); t1 += CVT1(u3);
        k += 4;
    }
    for (; k < e; k++) {
        u32 u = Xl[(size_t)adj[k] << 6];
        s0 += CVT0(u); s1 += CVT1(u);
    }
    out[((size_t)node << 6) + l] = (u32)f2bf(s0 + t0) | ((u32)f2bf(s1 + t1) << 16);
#undef CVT0
#undef CVT1
}

// ---------------- bf16 MFMA GEMM: out[N x 128] = A[N x 128] @ W^T + bias ----------------
// Wt: bf16 transposed [col][k] in swizzled LDS. A fragments loaded DIRECTLY from global.
// bf16 output path stages the 128x128 tile in LDS (swizzled) and stores coalesced uint4.
// Column stats written as per-block partials (coalesced, no atomics).
template <int OUT_BF16>
__global__ __launch_bounds__(256) void gemm_mfma_kernel(const u16* __restrict__ A,
                                                        const u16* __restrict__ Wt,
                                                        const float* __restrict__ bias,
                                                        void* __restrict__ outp,
                                                        float* __restrict__ psumB,
                                                        float* __restrict__ psqB, int nrows) {
    __shared__ __align__(16) u16 sW[16384];  // W staging, then bf16 output staging (32 KB)
    __shared__ float sred[1024];             // stats reduction buffer (4 KB)

    int tid = threadIdx.x;
    int rb = blockIdx.x * 128;

    // stage W (swizzled)
    {
        const uint4* g = (const uint4*)Wt;
#pragma unroll
        for (int p = 0; p < 8; p++) {
            int q = p * 256 + tid;
            int r = q >> 4, seg = q & 15;
            uint4 v = g[q];
            *(uint4*)((char*)sW + r * 256 + ((seg * 16) ^ ((r & 7) << 4))) = v;
        }
    }

    int l = tid & 63, w = tid >> 6;
    int lr = l & 15, lg = l >> 4;

    // preload all A fragments (8 x dwordx4 in flight)
    bf16x8 afr[2][4];
#pragma unroll
    for (int t = 0; t < 2; t++) {
        int grow = rb + w * 32 + t * 16 + lr;
        bool ok = grow < nrows;
#pragma unroll
        for (int kc = 0; kc < 4; kc++) {
            bf16x8 z = {0, 0, 0, 0, 0, 0, 0, 0};
            if (ok) z = *(const bf16x8*)(A + (size_t)grow * 128 + kc * 32 + lg * 8);
            afr[t][kc] = z;
        }
    }
    __syncthreads();

    f32x4 acc[2][8];
#pragma unroll
    for (int t = 0; t < 2; t++)
#pragma unroll
        for (int c = 0; c < 8; c++) acc[t][c] = (f32x4){0.f, 0.f, 0.f, 0.f};

#pragma unroll
    for (int kc = 0; kc < 4; kc++) {
        int kb2 = (kc * 32 + lg * 8) * 2;   // byte offset along k
        bf16x8 b[8];
#pragma unroll
        for (int c = 0; c < 8; c++) {
            int col = c * 16 + lr;
            b[c] = *(const bf16x8*)((const char*)sW + col * 256 + (kb2 ^ ((col & 7) << 4)));
        }
#pragma unroll
        for (int t = 0; t < 2; t++)
#pragma unroll
            for (int c = 0; c < 8; c++)
                acc[t][c] = __builtin_amdgcn_mfma_f32_16x16x32_bf16(afr[t][kc], b[c], acc[t][c], 0, 0, 0);
    }

    // epilogue: bias add, stats, store
    float bb[8];
#pragma unroll
    for (int c = 0; c < 8; c++) bb[c] = bias[c * 16 + lr];

    float sp[8], qp[8];
#pragma unroll
    for (int c = 0; c < 8; c++) { sp[c] = 0.f; qp[c] = 0.f; }

    if (OUT_BF16) {
        __syncthreads();   // sW (W staging) no longer read; reuse for output tile
#pragma unroll
        for (int t = 0; t < 2; t++) {
#pragma unroll
            for (int r = 0; r < 4; r++) {
                int row = w * 32 + t * 16 + lg * 4 + r;
                bool ok = (rb + row) < nrows;
#pragma unroll
                for (int c = 0; c < 8; c++) {
                    float v = acc[t][c][r] + bb[c];
                    int col = c * 16 + lr;
                    *(u16*)((char*)sW + ((row * 256 + col * 2) ^ ((row & 7) << 4))) = f2bf(v);
                    if (ok) { sp[c] += v; qp[c] += v * v; }
                }
            }
        }
        __syncthreads();
        // coalesced store: 8 x uint4 per thread (1KB/wave lines)
        u16* outB = (u16*)outp;
#pragma unroll
        for (int p = 0; p < 8; p++) {
            int q = p * 256 + tid;
            int row = q >> 4, seg = q & 15;
            int grow = rb + row;
            if (grow < nrows) {
                uint4 v = *(const uint4*)((char*)sW + ((row * 256 + seg * 16) ^ ((row & 7) << 4)));
                *(uint4*)(outB + (size_t)grow * 128 + seg * 8) = v;
            }
        }
    } else {
        float* outF = (float*)outp;
#pragma unroll
        for (int t = 0; t < 2; t++) {
#pragma unroll
            for (int r = 0; r < 4; r++) {
                int grow = rb + w * 32 + t * 16 + lg * 4 + r;
                bool ok = grow < nrows;
#pragma unroll
                for (int c = 0; c < 8; c++) {
                    float v = acc[t][c][r] + bb[c];
                    if (ok) {
                        outF[(size_t)grow * 128 + c * 16 + lr] = v;
                        sp[c] += v;
                        qp[c] += v * v;
                    }
                }
            }
        }
    }

#pragma unroll
    for (int c = 0; c < 8; c++) {
        sp[c] += __shfl_xor(sp[c], 16); sp[c] += __shfl_xor(sp[c], 32);
        qp[c] += __shfl_xor(qp[c], 16); qp[c] += __shfl_xor(qp[c], 32);
    }
    if (lg == 0) {
#pragma unroll
        for (int c = 0; c < 8; c++) {
            sred[(((w * 8 + c) * 16) + lr) * 2 + 0] = sp[c];
            sred[(((w * 8 + c) * 16) + lr) * 2 + 1] = qp[c];
        }
    }
    __syncthreads();
    if (tid < 128) {
        int c = tid >> 4, r = tid & 15;
        float s = 0.f, q = 0.f;
#pragma unroll
        for (int ww = 0; ww < 4; ww++) {
            s += sred[(((ww * 8 + c) * 16) + r) * 2 + 0];
            q += sred[(((ww * 8 + c) * 16) + r) * 2 + 1];
        }
        psumB[blockIdx.x * 128 + tid] = s;
        psqB[blockIdx.x * 128 + tid] = q;
    }
}

// ---------------- stats reduce: 128 blocks (one per feature) x 256 thr ----------------
// MODE 0: outS/outQ = raw S,Q (consumed by bnfold).
// MODE 1: fused BN2+outer-BN finalize -> outS=scale, outQ=shift.
template <int MODE>
__global__ __launch_bounds__(256) void stats_reduce_kernel(const float* __restrict__ psumB,
                                                           const float* __restrict__ psqB,
                                                           const float* __restrict__ g,
                                                           const float* __restrict__ bt,
                                                           const float* __restrict__ og,
                                                           const float* __restrict__ ob,
                                                           float* __restrict__ outS,
                                                           float* __restrict__ outQ) {
    int f = blockIdx.x;
    int t = threadIdx.x;
    float s = 0.f, q = 0.f;
    for (int b = t; b < GEMM_BLOCKS; b += 256) {
        s += psumB[b * 128 + f];
        q += psqB[b * 128 + f];
    }
#pragma unroll
    for (int off = 1; off < 64; off <<= 1) {
        s += __shfl_xor(s, off);
        q += __shfl_xor(q, off);
    }
    __shared__ float rs[4], rq[4];
    int w = t >> 6;
    if ((t & 63) == 0) { rs[w] = s; rq[w] = q; }
    __syncthreads();
    if (t == 0) {
        float S = rs[0] + rs[1] + rs[2] + rs[3];
        float Q = rq[0] + rq[1] + rq[2] + rq[3];
        if (MODE == 0) {
            outS[f] = S;
            outQ[f] = Q;
        } else {
            float m = S / (float)N_NODES;
            float v = Q / (float)N_NODES - m * m;
            if (v < 0.f) v = 0.f;
            float r2 = rsqrtf(v + BN_EPS);
            float a = r2 * g[f];
            float vu = v * a * a;
            float r3 = rsqrtf(vu + BN_EPS);
            float sc = a * r3 * og[f];
            outS[f] = sc;
            outQ[f] = ob[f] - m * sc;
        }
    }
}

// ---------------- BN1 finalize fused into W2 fold (128 blocks x 128 thr) ----------------
__global__ __launch_bounds__(128) void bnfold_kernel(const float* __restrict__ psum,
                                                     const float* __restrict__ psq,
                                                     const float* __restrict__ g,
                                                     const float* __restrict__ bt,
                                                     const float* __restrict__ W2,
                                                     const float* __restrict__ b2,
                                                     u16* __restrict__ W2ft,
                                                     float* __restrict__ b2f) {
    __shared__ float sc1[128], sh1[128];
    int k = threadIdx.x;
    int j = blockIdx.x;
    {
        float S = psum[k], Q = psq[k];
        float m = S / (float)N_NODES;
        float v = Q / (float)N_NODES - m * m;
        if (v < 0.f) v = 0.f;
        float r = rsqrtf(v + BN_EPS);
        float sc = r * g[k];
        sc1[k] = sc;
        sh1[k] = bt[k] - m * sc;
    }
    __syncthreads();
    float w = W2[k * 128 + j];
    W2ft[j * 128 + k] = f2bf(sc1[k] * w);
    float p = sh1[k] * w;
#pragma unroll
    for (int off = 1; off < 64; off <<= 1) p += __shfl_xor(p, off);
    __shared__ float r2[2];
    if ((k & 63) == 0) r2[k >> 6] = p;
    __syncthreads();
    if (k == 0) b2f[j] = b2[j] + r2[0] + r2[1];
}

// ---------------- weight prep: all layers at once ----------------
__global__ void w1_prep_kernel(const float* __restrict__ W, u16* __restrict__ Wt) {
    int q = blockIdx.x * 256 + threadIdx.x;   // 192 blocks x 256 = 3*16384
    int layer = q >> 14;
    int r = q & 16383;
    int j = r >> 7, k = r & 127;
    Wt[q] = f2bf(W[layer * 16384 + k * 128 + j]);
}

// ---------------- relu-affine, final layer: fp32 in-place ----------------
__global__ __launch_bounds__(256) void relu_affine_final_kernel(float* __restrict__ H,
                                                                const float* __restrict__ scale,
                                                                const float* __restrict__ shift) {
    size_t i4 = (size_t)blockIdx.x * 256 + threadIdx.x;
    int fb = ((int)(i4 & 31)) * 4;
    float4 h = ((const float4*)H)[i4];
    float4 sc = *(const float4*)&scale[fb];
    float4 sh = *(const float4*)&shift[fb];
    float4 y;
    y.x = fmaxf(h.x * sc.x + sh.x, 0.f);
    y.y = fmaxf(h.y * sc.y + sh.y, 0.f);
    y.z = fmaxf(h.z * sc.z + sh.z, 0.f);
    y.w = fmaxf(h.w * sc.w + sh.w, 0.f);
    ((float4*)H)[i4] = y;
}

// ---------------- readout ----------------
__global__ __launch_bounds__(128) void graph_embed_part_kernel(const float* __restrict__ X,
                                                               const float* __restrict__ w,
                                                               const int* __restrict__ batch,
                                                               float* __restrict__ gpart) {
    int g = blockIdx.x;
    int sl = blockIdx.y;
    int f = threadIdx.x;
    int lo = 0, hi = N_NODES;
    while (lo < hi) { int mid = (lo + hi) >> 1; if (batch[mid] < g) lo = mid + 1; else hi = mid; }
    int s = lo;
    lo = 0; hi = N_NODES;
    while (lo < hi) { int mid = (lo + hi) >> 1; if (batch[mid] < g + 1) lo = mid + 1; else hi = mid; }
    int e = lo;
    int cnt = e - s;
    int per = (cnt + GE_SLICES - 1) / GE_SLICES;
    int rs = s + sl * per;
    int re = rs + per; if (re > e) re = e;
    float acc = 0.f;
    for (int r = rs; r < re; r++) acc += X[(size_t)r * DF + f] * w[r];
    gpart[((size_t)g * GE_SLICES + sl) * DF + f] = acc;
}

// reduce slices -> ge, and fused final FC -> cls
__global__ __launch_bounds__(128) void graph_embed_reduce_kernel(const float* __restrict__ gpart,
                                                                 const float* __restrict__ fcW,
                                                                 const float* __restrict__ fcb,
                                                                 float* __restrict__ ge,
                                                                 float* __restrict__ cls) {
    int g = blockIdx.x, f = threadIdx.x;
    float a = 0.f;
#pragma unroll
    for (int s = 0; s < GE_SLICES; s++) a += gpart[((size_t)g * GE_SLICES + s) * DF + f];
    ge[g * DF + f] = a;
    // fused final_fc: cls[g][c] = fcb[c] + sum_f a*fcW[f][c]
    float p0 = a * fcW[f * NC + 0];
    float p1 = a * fcW[f * NC + 1];
#pragma unroll
    for (int off = 1; off < 64; off <<= 1) {
        p0 += __shfl_xor(p0, off);
        p1 += __shfl_xor(p1, off);
    }
    __shared__ float red[2][2];
    if ((f & 63) == 0) { red[f >> 6][0] = p0; red[f >> 6][1] = p1; }
    __syncthreads();
    if (f < NC) cls[g * NC + f] = fcb[f] + red[0][f] + red[1][f];
}

// ---------------- launcher ----------------
extern "C" void kernel_launch(void* const* d_in, const int* in_sizes, int n_in,
                              void* d_out, int out_size, void* d_ws, size_t ws_size,
                              hipStream_t stream) {
    const float* x    = (const float*)d_in[0];
    const int*   ei   = (const int*)d_in[1];
    const int*   src  = ei;
    const int*   dst  = ei + N_EDGES;
    const float* nw   = (const float*)d_in[2];
    const int*   batch= (const int*)d_in[3];
    const float* W1   = (const float*)d_in[4];
    const float* b1   = (const float*)d_in[5];
    const float* g1   = (const float*)d_in[6];
    const float* bt1  = (const float*)d_in[7];
    const float* W2   = (const float*)d_in[8];
    const float* b2   = (const float*)d_in[9];
    const float* g2   = (const float*)d_in[10];
    const float* bt2  = (const float*)d_in[11];
    const float* og   = (const float*)d_in[12];
    const float* ob   = (const float*)d_in[13];
    const float* fcW  = (const float*)d_in[14];
    const float* fcb  = (const float*)d_in[15];

    float* out_f    = (float*)d_out;
    float* node_out = out_f;                              // N*DF fp32
    float* ge       = out_f + (size_t)N_NODES * DF;       // G*DF
    float* cls      = ge + NG * DF;                       // G*C

    char* w = (char*)d_ws;
    auto alloc = [&](size_t bytes) { char* p = w; w += (bytes + 255) & ~(size_t)255; return p; };

    u16*   XB      = (u16*)alloc((size_t)N_NODES * DF * 2);     // bf16: cvt'd x, then raw h2
    u16*   AGG     = (u16*)alloc((size_t)N_NODES * DF * 2);     // bf16 agg output
    u16*   H1      = (u16*)alloc((size_t)N_NODES * DF * 2);     // bf16 h1_raw
    int*   offsets = (int*)alloc((size_t)(N_NODES + 1) * 4);
    int*   adj     = (int*)alloc((size_t)N_EDGES * 4);
    float* psumB   = (float*)alloc((size_t)GEMM_BLOCKS * 128 * 4);
    float* psqB    = (float*)alloc((size_t)GEMM_BLOCKS * 128 * 4);
    float* sF      = (float*)alloc(128 * 4);
    float* qF      = (float*)alloc(128 * 4);
    u16*   W1t     = (u16*)alloc((size_t)NL * 16384 * 2);
    u16*   W2ft    = (u16*)alloc(16384 * 2);
    float* b2f     = (float*)alloc(128 * 4);
    float* scaleO  = (float*)alloc(128 * 4);
    float* shiftO  = (float*)alloc(128 * 4);
    float* gpart   = (float*)alloc((size_t)NG * GE_SLICES * DF * 4);
    int*   blkhist = (int*)alloc((size_t)NBKT * NBIN_BLOCKS * 4);
    int*   bkt_tot = (int*)alloc(NBKT * 4);
    int*   bktbase = (int*)alloc((NBKT + 1) * 4);

    // pairs buffer (12.8MB) aliases AGG (dead until first agg_kernel)
    u64* pairs = (u64*)AGG;

    // bf16 mirror of input x + weight transposes
    cvt_x_kernel<<<12500, 256, 0, stream>>>(x, XB);
    w1_prep_kernel<<<192, 256, 0, stream>>>(W1, W1t);

    // ---- CSR build: bucket sort + one-shot per-bucket offsets/adj ----
    bin_count_kernel<<<NBIN_BLOCKS, 256, 0, stream>>>(dst, blkhist);
    binscanA_kernel<<<NBKT, NBIN_BLOCKS, 0, stream>>>(blkhist, bkt_tot);
    binscanB_kernel<<<1, 128, 0, stream>>>(bkt_tot, bktbase);
    bin_scatter_kernel<<<NBIN_BLOCKS, 256, 0, stream>>>(src, dst, blkhist, bktbase, pairs);
    csr_build_kernel<<<NBKT, 1024, 0, stream>>>(pairs, bktbase, offsets, adj);

    for (int l = 0; l < NL; l++) {
        // agg = x_i + sum x_j ; layers >0 fuse x = relu(h2*scaleO+shiftO) into the gather
        if (l == 0) {
            agg_kernel<0><<<N_NODES / 4, 256, 0, stream>>>((const u32*)XB, offsets, adj,
                                                           nullptr, nullptr, (u32*)AGG);
        } else {
            agg_kernel<1><<<N_NODES / 4, 256, 0, stream>>>((const u32*)XB, offsets, adj,
                                                           scaleO, shiftO, (u32*)AGG);
        }
        // h1_raw = agg @ W1 + b1 (bf16 out, LDS-transposed store) + per-block BN1 stats
        gemm_mfma_kernel<1><<<GEMM_BLOCKS, 256, 0, stream>>>(AGG, W1t + (size_t)l * 16384,
                                                             b1 + l * DF, H1, psumB, psqB,
                                                             N_NODES);
        // parallel stats reduce, then BN1 finalize fused into W2 fold
        stats_reduce_kernel<0><<<128, 256, 0, stream>>>(psumB, psqB, nullptr, nullptr,
                                                        nullptr, nullptr, sF, qF);
        bnfold_kernel<<<128, 128, 0, stream>>>(sF, qF, g1 + l * DF, bt1 + l * DF,
                                               W2 + (size_t)l * DF * DF, b2 + l * DF, W2ft, b2f);
        // h2_raw = h1_raw @ W2f + b2f (+ per-block stats); bf16->XB for l<2, fp32 for final
        if (l < NL - 1) {
            gemm_mfma_kernel<1><<<GEMM_BLOCKS, 256, 0, stream>>>(H1, W2ft, b2f, XB,
                                                                 psumB, psqB, N_NODES);
        } else {
            gemm_mfma_kernel<0><<<GEMM_BLOCKS, 256, 0, stream>>>(H1, W2ft, b2f, node_out,
                                                                 psumB, psqB, N_NODES);
        }
        // fused stats reduce + BN2/outer-BN finalize
        stats_reduce_kernel<1><<<128, 256, 0, stream>>>(psumB, psqB, g2 + l * DF, bt2 + l * DF,
                                                        og + l * DF, ob + l * DF, scaleO, shiftO);
        if (l == NL - 1) {
            relu_affine_final_kernel<<<12500, 256, 0, stream>>>(node_out, scaleO, shiftO);
        }
    }

    graph_embed_part_kernel<<<dim3(NG, GE_SLICES), 128, 0, stream>>>(node_out, nw, batch, gpart);
    graph_embed_reduce_kernel<<<NG, 128, 0, stream>>>(gpart, fcW, fcb, ge, cls);
}